// Round 1
// baseline (175.062 us; speedup 1.0000x reference)
//
#include <hip/hip_runtime.h>
#include <hip/hip_bf16.h>

typedef __attribute__((ext_vector_type(8))) short short8;
typedef __attribute__((ext_vector_type(4))) float floatx4;
typedef unsigned int u32;

#define NN 4096

static __device__ __forceinline__ unsigned f2bf_rne(float x) {
    union { float f; unsigned u; } v; v.f = x;
    unsigned r = v.u + 0x7fffu + ((v.u >> 16) & 1u);
    return r >> 16;
}
static __device__ __forceinline__ float bf2f(unsigned hi) {
    union { unsigned u; float f; } v; v.u = hi << 16; return v.f;
}

// async global->LDS DMA, 16 B per lane; dest = wave-uniform base + lane*16
static __device__ __forceinline__ void gld16(void* l, const void* g) {
    __builtin_amdgcn_global_load_lds(
        (const __attribute__((address_space(1))) u32*)g,
        (__attribute__((address_space(3))) u32*)l, 16, 0, 0);
}

// ---- wc: ONE block computes Wc^T = (W1@W2)^T [64 n][68 k] f32 and
// w1a = {W1@aL, W1@aR} into workspace. Removes the per-block redundant
// scalar GEMM that made prep co-dominant (~55-60us).
__global__ __launch_bounds__(256, 1)
void wc_kernel(const float* __restrict__ W1,
               const float* __restrict__ W2,
               const float* __restrict__ alpha,
               float* __restrict__ WcstG,
               float* __restrict__ w1aG) {
    __shared__ __align__(16) float W1s[64 * 68];
    __shared__ __align__(16) float W2s[64 * 68];
    __shared__ float als[128];
    const int t = threadIdx.x;
    #pragma unroll
    for (int s = 0; s < 4; ++s) {
        int idx = s * 1024 + t * 4;
        int r = idx >> 6, cc = idx & 63;
        *(float4*)&W1s[r * 68 + cc] = *(const float4*)(W1 + idx);
        *(float4*)&W2s[r * 68 + cc] = *(const float4*)(W2 + idx);
    }
    if (t < 128) als[t] = alpha[t];
    __syncthreads();
    const int k = t >> 2, nq = t & 3;
    float acc[16];
    #pragma unroll
    for (int i = 0; i < 16; ++i) acc[i] = 0.f;
    for (int mm = 0; mm < 64; ++mm) {
        float w1v = W1s[k * 68 + mm];
        #pragma unroll
        for (int i = 0; i < 16; ++i)
            acc[i] += w1v * W2s[mm * 68 + nq * 16 + i];
    }
    #pragma unroll
    for (int i = 0; i < 16; ++i)
        WcstG[(nq * 16 + i) * 68 + k] = acc[i];
    if (t < 64) {
        float sl = 0.f, sr = 0.f;
        for (int cc2 = 0; cc2 < 64; ++cc2) {
            float wv = W1s[t * 68 + cc2];
            sl += wv * als[cc2];
            sr += wv * als[64 + cc2];
        }
        w1aG[t] = sl; w1aG[64 + t] = sr;
    }
}

// ---- prep: G = X@Wc (bf16 hi/lo MFMA) -> Gt bf16 [b*64+c][4096]; lv/rv fp32.
// Wc^T and w1a now loaded from workspace (L2 broadcast) instead of recomputed.
__global__ __launch_bounds__(256, 4)
void prep_kernel(const float* __restrict__ X,
                 const float* __restrict__ WcstG,
                 const float* __restrict__ w1aG,
                 unsigned short* __restrict__ Gt,
                 float* __restrict__ lv,
                 float* __restrict__ rv) {
    __shared__ __align__(16) char sm[17920];
    float* Wcst = (float*)sm;                 // [64 n][68 k]
    float* w1s  = (float*)(sm + 17408);       // [128]
    float* GsT  = (float*)sm;                 // epilogue reuse: [64][68]

    const int t = threadIdx.x;
    const int row0 = blockIdx.x * 64;         // flat b*N + n
    const int b = row0 >> 12, n0 = row0 & (NN - 1);
    const int w = t >> 6, lane = t & 63;
    const int m = lane & 15, q = lane >> 4;

    // issue X loads early (consumed much later)
    const int row = row0 + w * 16 + m;
    const float* xp = X + (size_t)row * 64;
    float4 x0 = *(const float4*)(xp + q * 8);
    float4 x1 = *(const float4*)(xp + q * 8 + 4);
    float4 x2 = *(const float4*)(xp + 32 + q * 8);
    float4 x3 = *(const float4*)(xp + 32 + q * 8 + 4);

    // stage Wc^T + w1a from workspace
    #pragma unroll
    for (int it = 0; it < 5; ++it) {
        int i = it * 1024 + t * 4;
        if (i < 4352) *(float4*)&Wcst[i] = *(const float4*)(WcstG + i);
    }
    if (t < 128) w1s[t] = w1aG[t];
    __syncthreads();

    const float xs[16] = {x0.x,x0.y,x0.z,x0.w, x1.x,x1.y,x1.z,x1.w,
                          x2.x,x2.y,x2.z,x2.w, x3.x,x3.y,x3.z,x3.w};

    // lv/rv fp32
    float pl = 0.f, pr = 0.f;
    #pragma unroll
    for (int ks = 0; ks < 2; ++ks)
        #pragma unroll
        for (int j = 0; j < 8; ++j) {
            int k = ks * 32 + q * 8 + j;
            float xv = xs[ks * 8 + j];
            pl += xv * w1s[k];
            pr += xv * w1s[64 + k];
        }
    pl += __shfl_xor(pl, 16, 64); pl += __shfl_xor(pl, 32, 64);
    pr += __shfl_xor(pr, 16, 64); pr += __shfl_xor(pr, 32, 64);
    if (q == 0) { lv[row] = pl; rv[row] = pr; }

    // bf16 hi/lo A-fragments
    short8 ah[2], al[2];
    #pragma unroll
    for (int ks = 0; ks < 2; ++ks)
        #pragma unroll
        for (int j = 0; j < 8; ++j) {
            float f = xs[ks * 8 + j];
            unsigned hb = f2bf_rne(f);
            float res = f - bf2f(hb);
            ah[ks][j] = (short)hb;
            al[ks][j] = (short)f2bf_rne(res);
        }

    // B-frags from Wcst
    short8 bfr[4][2];
    #pragma unroll
    for (int nt = 0; nt < 4; ++nt)
        #pragma unroll
        for (int ks = 0; ks < 2; ++ks) {
            const float* wp = &Wcst[(nt * 16 + m) * 68 + ks * 32 + q * 8];
            float4 w0 = *(const float4*)wp;
            float4 w1 = *(const float4*)(wp + 4);
            short8 bf;
            bf[0] = (short)f2bf_rne(w0.x); bf[1] = (short)f2bf_rne(w0.y);
            bf[2] = (short)f2bf_rne(w0.z); bf[3] = (short)f2bf_rne(w0.w);
            bf[4] = (short)f2bf_rne(w1.x); bf[5] = (short)f2bf_rne(w1.y);
            bf[6] = (short)f2bf_rne(w1.z); bf[7] = (short)f2bf_rne(w1.w);
            bfr[nt][ks] = bf;
        }

    floatx4 acc[4] = {{0,0,0,0},{0,0,0,0},{0,0,0,0},{0,0,0,0}};
    #pragma unroll
    for (int ks = 0; ks < 2; ++ks)
        #pragma unroll
        for (int nt = 0; nt < 4; ++nt) {
            acc[nt] = __builtin_amdgcn_mfma_f32_16x16x32_bf16(ah[ks], bfr[nt][ks], acc[nt], 0, 0, 0);
            acc[nt] = __builtin_amdgcn_mfma_f32_16x16x32_bf16(al[ks], bfr[nt][ks], acc[nt], 0, 0, 0);
        }

    __syncthreads();    // all Wcst reads done; sm@0 reused as GsT
    #pragma unroll
    for (int nt = 0; nt < 4; ++nt)
        #pragma unroll
        for (int rg = 0; rg < 4; ++rg)
            GsT[(nt * 16 + m) * 68 + w * 16 + q * 4 + rg] = acc[nt][rg];
    __syncthreads();
    unsigned* Gu = (unsigned*)Gt;
    #pragma unroll
    for (int it2 = 0; it2 < 8; ++it2) {
        int c2 = (t >> 5) + it2 * 8;
        int np = t & 31;
        unsigned lo = f2bf_rne(GsT[c2 * 68 + 2 * np]);
        unsigned hi = f2bf_rne(GsT[c2 * 68 + 2 * np + 1]);
        Gu[(((((size_t)(b * 64 + c2)) << 12) + n0) >> 1) + np] = lo | (hi << 16);
    }
}

// ---- attn v2: block = (i-tile 64, b), 1024 thr = 4 j-groups x 4 waves.
// E computed IN-REGISTER in the MFMA A-frag consumer layout (thread owns
// row wsub*16+m, cols q*8..+8) -> no Es LDS staging, no transpose.
// Denominator summed on VALU from the same bf16-rounded E values -> no
// ones-MFMA. G staged via global_load_lds into a lane-linear 4-buffer ring
// (read addr = base + nt*1024 + lane*16: conflict-free). ONE barrier per
// chunk (its implicit vmcnt(0) drains the DMA); buffer reuse separated by
// two barriers -> race-free. A/rv prefetched one chunk ahead in registers.
__global__ __launch_bounds__(1024, 4)
void attn_kernel(const float* __restrict__ A,
                 const unsigned short* __restrict__ Gt,
                 const float* __restrict__ lv,
                 const float* __restrict__ rv,
                 float* __restrict__ out) {
    // LDS: Gbuf[4 buf][4 grp][4 wsub][64 lanes * 16B] = 65536 B.
    // Epilogue reuses sm as red[2][64][68] f32 (34816 B).
    __shared__ __align__(16) char sm[65536];

    const int bx = blockIdx.x;
    const int i0 = (bx & 63) * 64;
    const int b  = bx >> 6;
    const int t = threadIdx.x;
    const int wave = t >> 6, lane = t & 63;
    const int grp = wave >> 2, wsub = wave & 3;
    const int m = lane & 15, q = lane >> 4;
    const int irow = wsub * 16 + m;           // row for E; channel for G staging

    const float* aRow = A + (size_t)(i0 + irow) * NN + grp * 1024 + q * 8;
    const unsigned short* gRow = Gt + (((size_t)(b * 64 + irow)) << 12) + grp * 1024 + q * 8;
    const float* rvg = rv + (size_t)b * NN + grp * 1024 + q * 8;
    char* gdst = sm + grp * 4096 + wsub * 1024;   // wave-uniform DMA dest (buf 0)

    const float li = lv[b * NN + i0 + irow] * 1.44269504f;   // fold log2e
    const float li001 = li * 0.01f;                          // leaky slope (scale>0 commutes)

    // prologue: DMA chunk 0 into buf 0; prefetch A/rv chunk 0 into regs
    gld16(gdst, gRow);
    float4 a0 = *(const float4*)(aRow);
    float4 a1 = *(const float4*)(aRow + 4);
    float4 r0 = *(const float4*)(rvg);
    float4 r1 = *(const float4*)(rvg + 4);

    const bool diag_grp = ((i0 >> 10) == grp);     // uniform: i0%1024+63 < 1024
    const int jd = (i0 + irow) - grp * 1024;

    floatx4 acc0 = {0,0,0,0}, acc1 = {0,0,0,0}, acc2 = {0,0,0,0}, acc3 = {0,0,0,0};
    float dsum = 0.f;

    unsigned short* Gbuf = (unsigned short*)sm;

    #pragma unroll 4
    for (int cc = 0; cc < 32; ++cc) {
        // DMA next chunk (drained by this iteration's barrier)
        if (cc < 31) gld16(gdst + ((cc + 1) & 3) * 16384, gRow + (cc + 1) * 32);

        // ---- E in consumer layout ----
        float aa[8] = {a0.x, a0.y, a0.z, a0.w, a1.x, a1.y, a1.z, a1.w};
        if (diag_grp && ((jd >> 5) == cc)) {       // adj diag := 1
            const int dd = jd - (cc * 32 + q * 8);
            #pragma unroll
            for (int e = 0; e < 8; ++e) if (dd == e) aa[e] = 1.0f;
        }
        const float rr[8] = {r0.x, r0.y, r0.z, r0.w, r1.x, r1.y, r1.z, r1.w};
        unsigned up[8];
        #pragma unroll
        for (int e = 0; e < 8; ++e) {
            float s = fmaxf(li * rr[e], li001 * rr[e]);        // leaky(li*r)
            float ev = __builtin_amdgcn_exp2f(s) * aa[e];
            unsigned u = __float_as_uint(ev) + 0x8000u;
            up[e] = u;
            dsum += __uint_as_float(u & 0xffff0000u);          // den = sum of SAME bf16 vals
        }
        union { unsigned u[4]; short8 s8; } cv;
        cv.u[0] = __builtin_amdgcn_perm(up[1], up[0], 0x07060302u);
        cv.u[1] = __builtin_amdgcn_perm(up[3], up[2], 0x07060302u);
        cv.u[2] = __builtin_amdgcn_perm(up[5], up[4], 0x07060302u);
        cv.u[3] = __builtin_amdgcn_perm(up[7], up[6], 0x07060302u);
        const short8 afr = cv.s8;

        // prefetch next chunk's A/rv (consumed next iteration)
        { const int jn = (cc < 31) ? (cc + 1) * 32 : 0;        // clamp tail
          a0 = *(const float4*)(aRow + jn);
          a1 = *(const float4*)(aRow + jn + 4);
          r0 = *(const float4*)(rvg + jn);
          r1 = *(const float4*)(rvg + jn + 4); }

        __syncthreads();   // drains DMA (chunk cc staged by iter cc-1 already done)
        {
            const unsigned short* Gb = Gbuf + (cc & 3) * 8192 + grp * 2048;
            const short8 b0 = *(const short8*)&Gb[lane * 8];
            const short8 b1 = *(const short8*)&Gb[512 + lane * 8];
            const short8 b2 = *(const short8*)&Gb[1024 + lane * 8];
            const short8 b3 = *(const short8*)&Gb[1536 + lane * 8];
            acc0 = __builtin_amdgcn_mfma_f32_16x16x32_bf16(afr, b0, acc0, 0, 0, 0);
            acc1 = __builtin_amdgcn_mfma_f32_16x16x32_bf16(afr, b1, acc1, 0, 0, 0);
            acc2 = __builtin_amdgcn_mfma_f32_16x16x32_bf16(afr, b2, acc2, 0, 0, 0);
            acc3 = __builtin_amdgcn_mfma_f32_16x16x32_bf16(afr, b3, acc3, 0, 0, 0);
        }
    }

    // den: reduce over the 4 q-lanes of each row
    dsum += __shfl_xor(dsum, 16, 64);
    dsum += __shfl_xor(dsum, 32, 64);

    // ---- epilogue: two-pass cross-group reduction in LDS, divide, store ----
    __syncthreads();
    float* red = (float*)sm;                 // [2][64][68]; col 64 holds den
    const int il = t >> 4, c4 = t & 15;
    float4 osum = {0.f, 0.f, 0.f, 0.f};
    float dtot = 0.f;
    #pragma unroll
    for (int pass = 0; pass < 2; ++pass) {
        if ((grp >> 1) == pass) {
            float* rp_ = red + (grp & 1) * 4352;
            #pragma unroll
            for (int nt = 0; nt < 4; ++nt) {
                floatx4 av = nt == 0 ? acc0 : nt == 1 ? acc1 : nt == 2 ? acc2 : acc3;
                #pragma unroll
                for (int rg = 0; rg < 4; ++rg)
                    rp_[(wsub * 16 + q * 4 + rg) * 68 + nt * 16 + m] = av[rg];
            }
            if (q == 0) rp_[(wsub * 16 + m) * 68 + 64] = dsum;
        }
        __syncthreads();
        {
            float4 v0 = *(const float4*)&red[il * 68 + c4 * 4];
            float4 v1 = *(const float4*)&red[4352 + il * 68 + c4 * 4];
            osum.x += v0.x + v1.x; osum.y += v0.y + v1.y;
            osum.z += v0.z + v1.z; osum.w += v0.w + v1.w;
            dtot += red[il * 68 + 64] + red[4352 + il * 68 + 64];
        }
        __syncthreads();
    }
    const float rinv = 1.0f / dtot;
    float4 o;
    o.x = osum.x * rinv; o.y = osum.y * rinv;
    o.z = osum.z * rinv; o.w = osum.w * rinv;
    *(float4*)(out + (((size_t)(b * NN + i0 + il)) << 6) + c4 * 4) = o;
}

extern "C" void kernel_launch(void* const* d_in, const int* in_sizes, int n_in,
                              void* d_out, int out_size, void* d_ws, size_t ws_size,
                              hipStream_t stream) {
    const float* X     = (const float*)d_in[0];
    const float* A     = (const float*)d_in[1];
    const float* W1    = (const float*)d_in[2];
    const float* W2    = (const float*)d_in[3];
    const float* alpha = (const float*)d_in[4];
    float* out = (float*)d_out;

    char* ws = (char*)d_ws;
    unsigned short* Gt = (unsigned short*)(ws);            // 2 MiB
    float* lvp   = (float*)(ws + 2097152);                 // 64 KiB
    float* rvp   = (float*)(ws + 2097152 + 65536);         // 64 KiB
    float* WcstG = (float*)(ws + 2097152 + 131072);        // 17408 B
    float* w1aG  = (float*)(ws + 2097152 + 131072 + 17408);// 512 B

    wc_kernel<<<1, 256, 0, stream>>>(W1, W2, alpha, WcstG, w1aG);
    prep_kernel<<<256, 256, 0, stream>>>(X, WcstG, w1aG, Gt, lvp, rvp);
    attn_kernel<<<256, 1024, 0, stream>>>(A, Gt, lvp, rvp, out);
}

// Round 2
// 168.502 us; speedup vs baseline: 1.0389x; 1.0389x over previous
//
#include <hip/hip_runtime.h>
#include <hip/hip_bf16.h>

typedef __attribute__((ext_vector_type(8))) short short8;
typedef __attribute__((ext_vector_type(4))) float floatx4;
typedef unsigned int u32;

#define NN 4096

static __device__ __forceinline__ unsigned f2bf_rne(float x) {
    union { float f; unsigned u; } v; v.f = x;
    unsigned r = v.u + 0x7fffu + ((v.u >> 16) & 1u);
    return r >> 16;
}
static __device__ __forceinline__ float bf2f(unsigned hi) {
    union { unsigned u; float f; } v; v.u = hi << 16; return v.f;
}

// async global->LDS DMA, 16 B per lane; dest = wave-uniform base + lane*16
static __device__ __forceinline__ void gld16(void* l, const void* g) {
    __builtin_amdgcn_global_load_lds(
        (const __attribute__((address_space(1))) u32*)g,
        (__attribute__((address_space(3))) u32*)l, 16, 0, 0);
}

// ---- wc: ONE block computes Wc^T = (W1@W2)^T [64 n][68 k] f32 and
// w1a = {W1@aL, W1@aR} into workspace.
__global__ __launch_bounds__(256, 1)
void wc_kernel(const float* __restrict__ W1,
               const float* __restrict__ W2,
               const float* __restrict__ alpha,
               float* __restrict__ WcstG,
               float* __restrict__ w1aG) {
    __shared__ __align__(16) float W1s[64 * 68];
    __shared__ __align__(16) float W2s[64 * 68];
    __shared__ float als[128];
    const int t = threadIdx.x;
    #pragma unroll
    for (int s = 0; s < 4; ++s) {
        int idx = s * 1024 + t * 4;
        int r = idx >> 6, cc = idx & 63;
        *(float4*)&W1s[r * 68 + cc] = *(const float4*)(W1 + idx);
        *(float4*)&W2s[r * 68 + cc] = *(const float4*)(W2 + idx);
    }
    if (t < 128) als[t] = alpha[t];
    __syncthreads();
    const int k = t >> 2, nq = t & 3;
    float acc[16];
    #pragma unroll
    for (int i = 0; i < 16; ++i) acc[i] = 0.f;
    for (int mm = 0; mm < 64; ++mm) {
        float w1v = W1s[k * 68 + mm];
        #pragma unroll
        for (int i = 0; i < 16; ++i)
            acc[i] += w1v * W2s[mm * 68 + nq * 16 + i];
    }
    #pragma unroll
    for (int i = 0; i < 16; ++i)
        WcstG[(nq * 16 + i) * 68 + k] = acc[i];
    if (t < 64) {
        float sl = 0.f, sr = 0.f;
        for (int cc2 = 0; cc2 < 64; ++cc2) {
            float wv = W1s[t * 68 + cc2];
            sl += wv * als[cc2];
            sr += wv * als[64 + cc2];
        }
        w1aG[t] = sl; w1aG[64 + t] = sr;
    }
}

// ---- prep: G = X@Wc (bf16 hi/lo MFMA) -> Gt bf16 [b*64+c][4096]; lv/rv fp32.
__global__ __launch_bounds__(256, 4)
void prep_kernel(const float* __restrict__ X,
                 const float* __restrict__ WcstG,
                 const float* __restrict__ w1aG,
                 unsigned short* __restrict__ Gt,
                 float* __restrict__ lv,
                 float* __restrict__ rv) {
    __shared__ __align__(16) char sm[17920];
    float* Wcst = (float*)sm;                 // [64 n][68 k]
    float* w1s  = (float*)(sm + 17408);       // [128]
    float* GsT  = (float*)sm;                 // epilogue reuse: [64][68]

    const int t = threadIdx.x;
    const int row0 = blockIdx.x * 64;         // flat b*N + n
    const int b = row0 >> 12, n0 = row0 & (NN - 1);
    const int w = t >> 6, lane = t & 63;
    const int m = lane & 15, q = lane >> 4;

    const int row = row0 + w * 16 + m;
    const float* xp = X + (size_t)row * 64;
    float4 x0 = *(const float4*)(xp + q * 8);
    float4 x1 = *(const float4*)(xp + q * 8 + 4);
    float4 x2 = *(const float4*)(xp + 32 + q * 8);
    float4 x3 = *(const float4*)(xp + 32 + q * 8 + 4);

    #pragma unroll
    for (int it = 0; it < 5; ++it) {
        int i = it * 1024 + t * 4;
        if (i < 4352) *(float4*)&Wcst[i] = *(const float4*)(WcstG + i);
    }
    if (t < 128) w1s[t] = w1aG[t];
    __syncthreads();

    const float xs[16] = {x0.x,x0.y,x0.z,x0.w, x1.x,x1.y,x1.z,x1.w,
                          x2.x,x2.y,x2.z,x2.w, x3.x,x3.y,x3.z,x3.w};

    float pl = 0.f, pr = 0.f;
    #pragma unroll
    for (int ks = 0; ks < 2; ++ks)
        #pragma unroll
        for (int j = 0; j < 8; ++j) {
            int k = ks * 32 + q * 8 + j;
            float xv = xs[ks * 8 + j];
            pl += xv * w1s[k];
            pr += xv * w1s[64 + k];
        }
    pl += __shfl_xor(pl, 16, 64); pl += __shfl_xor(pl, 32, 64);
    pr += __shfl_xor(pr, 16, 64); pr += __shfl_xor(pr, 32, 64);
    if (q == 0) { lv[row] = pl; rv[row] = pr; }

    short8 ah[2], al[2];
    #pragma unroll
    for (int ks = 0; ks < 2; ++ks)
        #pragma unroll
        for (int j = 0; j < 8; ++j) {
            float f = xs[ks * 8 + j];
            unsigned hb = f2bf_rne(f);
            float res = f - bf2f(hb);
            ah[ks][j] = (short)hb;
            al[ks][j] = (short)f2bf_rne(res);
        }

    short8 bfr[4][2];
    #pragma unroll
    for (int nt = 0; nt < 4; ++nt)
        #pragma unroll
        for (int ks = 0; ks < 2; ++ks) {
            const float* wp = &Wcst[(nt * 16 + m) * 68 + ks * 32 + q * 8];
            float4 w0 = *(const float4*)wp;
            float4 w1 = *(const float4*)(wp + 4);
            short8 bf;
            bf[0] = (short)f2bf_rne(w0.x); bf[1] = (short)f2bf_rne(w0.y);
            bf[2] = (short)f2bf_rne(w0.z); bf[3] = (short)f2bf_rne(w0.w);
            bf[4] = (short)f2bf_rne(w1.x); bf[5] = (short)f2bf_rne(w1.y);
            bf[6] = (short)f2bf_rne(w1.z); bf[7] = (short)f2bf_rne(w1.w);
            bfr[nt][ks] = bf;
        }

    floatx4 acc[4] = {{0,0,0,0},{0,0,0,0},{0,0,0,0},{0,0,0,0}};
    #pragma unroll
    for (int ks = 0; ks < 2; ++ks)
        #pragma unroll
        for (int nt = 0; nt < 4; ++nt) {
            acc[nt] = __builtin_amdgcn_mfma_f32_16x16x32_bf16(ah[ks], bfr[nt][ks], acc[nt], 0, 0, 0);
            acc[nt] = __builtin_amdgcn_mfma_f32_16x16x32_bf16(al[ks], bfr[nt][ks], acc[nt], 0, 0, 0);
        }

    __syncthreads();
    #pragma unroll
    for (int nt = 0; nt < 4; ++nt)
        #pragma unroll
        for (int rg = 0; rg < 4; ++rg)
            GsT[(nt * 16 + m) * 68 + w * 16 + q * 4 + rg] = acc[nt][rg];
    __syncthreads();
    unsigned* Gu = (unsigned*)Gt;
    #pragma unroll
    for (int it2 = 0; it2 < 8; ++it2) {
        int c2 = (t >> 5) + it2 * 8;
        int np = t & 31;
        unsigned lo = f2bf_rne(GsT[c2 * 68 + 2 * np]);
        unsigned hi = f2bf_rne(GsT[c2 * 68 + 2 * np + 1]);
        Gu[(((((size_t)(b * 64 + c2)) << 12) + n0) >> 1) + np] = lo | (hi << 16);
    }
}

// ---- attn v3: same dataflow as v2 but the loop barrier is now a raw
// s_barrier preceded by a COUNTED vmcnt (T3/T4) so prefetch DMAs stay in
// flight across barriers. DMA depth 2 into a 4-buffer ring.
// vmcnt(6) proof: gld16 issue slots are pinned by sched_barrier(0) fences;
// at barrier(cc), vmem ops issued after gld16(cc) = regloads(cc)x4 +
// gld16(cc+1) + regloads(cc+1)x4 [+ gld16(cc+2)] >= 8 always (>= 8 at the
// tail), and vmcnt retires in issue order, so vmcnt(6) forces gld16(cc)
// retired while keeping the 6 newest (next regloads + 2 DMAs) in flight.
// WAW: gld16(cc+2) writes buf[(cc+2)&3]; its previous readers (iter cc-2)
// consumed data (lgkm-drained before their MFMA) before barrier(cc-1),
// and the DMA is issued after barrier(cc-1) -> race-free.
__global__ __launch_bounds__(1024, 2)
void attn_kernel(const float* __restrict__ A,
                 const unsigned short* __restrict__ Gt,
                 const float* __restrict__ lv,
                 const float* __restrict__ rv,
                 float* __restrict__ out) {
    // LDS: Gbuf[4 buf][4 grp][4 wsub][64 lanes * 16B] = 65536 B.
    // Epilogue reuses sm as red[2][64][68] f32 (34816 B).
    __shared__ __align__(16) char sm[65536];

    const int bx = blockIdx.x;
    const int i0 = (bx & 63) * 64;
    const int b  = bx >> 6;
    const int t = threadIdx.x;
    const int wave = t >> 6, lane = t & 63;
    const int grp = wave >> 2, wsub = wave & 3;
    const int m = lane & 15, q = lane >> 4;
    const int irow = wsub * 16 + m;

    const float* aRow = A + (size_t)(i0 + irow) * NN + grp * 1024 + q * 8;
    const unsigned short* gRow = Gt + (((size_t)(b * 64 + irow)) << 12) + grp * 1024 + q * 8;
    const float* rvg = rv + (size_t)b * NN + grp * 1024 + q * 8;
    char* gdst = sm + grp * 4096 + wsub * 1024;   // wave-uniform DMA dest (buf 0)

    const float li = lv[b * NN + i0 + irow] * 1.44269504f;
    const float li001 = li * 0.01f;

    // prologue: DMA chunks 0,1 (pinned issue order); reg-prefetch chunk 0
    __builtin_amdgcn_sched_barrier(0);
    gld16(gdst, gRow);                            // chunk 0 -> buf 0
    __builtin_amdgcn_sched_barrier(0);
    gld16(gdst + 16384, gRow + 32);               // chunk 1 -> buf 1
    __builtin_amdgcn_sched_barrier(0);
    float4 a0 = *(const float4*)(aRow);
    float4 a1 = *(const float4*)(aRow + 4);
    float4 r0 = *(const float4*)(rvg);
    float4 r1 = *(const float4*)(rvg + 4);

    const bool diag_grp = ((i0 >> 10) == grp);
    const int jd = (i0 + irow) - grp * 1024;

    floatx4 acc0 = {0,0,0,0}, acc1 = {0,0,0,0}, acc2 = {0,0,0,0}, acc3 = {0,0,0,0};
    float dsum = 0.f;

    unsigned short* Gbuf = (unsigned short*)sm;

    #pragma unroll 2
    for (int cc = 0; cc < 32; ++cc) {
        // ---- E in consumer layout (regs loaded last iteration) ----
        float aa[8] = {a0.x, a0.y, a0.z, a0.w, a1.x, a1.y, a1.z, a1.w};
        if (diag_grp && ((jd >> 5) == cc)) {
            const int dd = jd - (cc * 32 + q * 8);
            #pragma unroll
            for (int e = 0; e < 8; ++e) if (dd == e) aa[e] = 1.0f;
        }
        const float rr[8] = {r0.x, r0.y, r0.z, r0.w, r1.x, r1.y, r1.z, r1.w};
        unsigned up[8];
        #pragma unroll
        for (int e = 0; e < 8; ++e) {
            float s = fmaxf(li * rr[e], li001 * rr[e]);        // leaky(li*r)
            float ev = __builtin_amdgcn_exp2f(s) * aa[e];
            unsigned u = __float_as_uint(ev) + 0x8000u;
            up[e] = u;
            dsum += __uint_as_float(u & 0xffff0000u);          // den = same bf16 vals
        }
        union { unsigned u[4]; short8 s8; } cv;
        cv.u[0] = __builtin_amdgcn_perm(up[1], up[0], 0x07060302u);
        cv.u[1] = __builtin_amdgcn_perm(up[3], up[2], 0x07060302u);
        cv.u[2] = __builtin_amdgcn_perm(up[5], up[4], 0x07060302u);
        cv.u[3] = __builtin_amdgcn_perm(up[7], up[6], 0x07060302u);
        const short8 afr = cv.s8;

        // reg-prefetch chunk cc+1's A/rv
        { const int jn = (cc < 31) ? (cc + 1) * 32 : 0;
          a0 = *(const float4*)(aRow + jn);
          a1 = *(const float4*)(aRow + jn + 4);
          r0 = *(const float4*)(rvg + jn);
          r1 = *(const float4*)(rvg + jn + 4); }

        // DMA chunk cc+2 (pinned slot)
        __builtin_amdgcn_sched_barrier(0);
        if (cc < 30) gld16(gdst + ((cc + 2) & 3) * 16384, gRow + (cc + 2) * 32);
        __builtin_amdgcn_sched_barrier(0);

        // counted-vmcnt barrier: gld16(cc) retired, 6 newest stay in flight
        asm volatile("s_waitcnt vmcnt(6)" ::: "memory");
        __builtin_amdgcn_s_barrier();
        __builtin_amdgcn_sched_barrier(0);

        {
            const unsigned short* Gb = Gbuf + (cc & 3) * 8192 + grp * 2048;
            const short8 b0 = *(const short8*)&Gb[lane * 8];
            const short8 b1 = *(const short8*)&Gb[512 + lane * 8];
            const short8 b2 = *(const short8*)&Gb[1024 + lane * 8];
            const short8 b3 = *(const short8*)&Gb[1536 + lane * 8];
            acc0 = __builtin_amdgcn_mfma_f32_16x16x32_bf16(afr, b0, acc0, 0, 0, 0);
            acc1 = __builtin_amdgcn_mfma_f32_16x16x32_bf16(afr, b1, acc1, 0, 0, 0);
            acc2 = __builtin_amdgcn_mfma_f32_16x16x32_bf16(afr, b2, acc2, 0, 0, 0);
            acc3 = __builtin_amdgcn_mfma_f32_16x16x32_bf16(afr, b3, acc3, 0, 0, 0);
        }
    }

    // den: reduce over the 4 q-lanes of each row
    dsum += __shfl_xor(dsum, 16, 64);
    dsum += __shfl_xor(dsum, 32, 64);

    // ---- epilogue: two-pass cross-group reduction in LDS, divide, store ----
    __syncthreads();
    float* red = (float*)sm;                 // [2][64][68]; col 64 holds den
    const int il = t >> 4, c4 = t & 15;
    float4 osum = {0.f, 0.f, 0.f, 0.f};
    float dtot = 0.f;
    #pragma unroll
    for (int pass = 0; pass < 2; ++pass) {
        if ((grp >> 1) == pass) {
            float* rp_ = red + (grp & 1) * 4352;
            #pragma unroll
            for (int nt = 0; nt < 4; ++nt) {
                floatx4 av = nt == 0 ? acc0 : nt == 1 ? acc1 : nt == 2 ? acc2 : acc3;
                #pragma unroll
                for (int rg = 0; rg < 4; ++rg)
                    rp_[(wsub * 16 + q * 4 + rg) * 68 + nt * 16 + m] = av[rg];
            }
            if (q == 0) rp_[(wsub * 16 + m) * 68 + 64] = dsum;
        }
        __syncthreads();
        {
            float4 v0 = *(const float4*)&red[il * 68 + c4 * 4];
            float4 v1 = *(const float4*)&red[4352 + il * 68 + c4 * 4];
            osum.x += v0.x + v1.x; osum.y += v0.y + v1.y;
            osum.z += v0.z + v1.z; osum.w += v0.w + v1.w;
            dtot += red[il * 68 + 64] + red[4352 + il * 68 + 64];
        }
        __syncthreads();
    }
    const float rinv = 1.0f / dtot;
    float4 o;
    o.x = osum.x * rinv; o.y = osum.y * rinv;
    o.z = osum.z * rinv; o.w = osum.w * rinv;
    *(float4*)(out + (((size_t)(b * NN + i0 + il)) << 6) + c4 * 4) = o;
}

extern "C" void kernel_launch(void* const* d_in, const int* in_sizes, int n_in,
                              void* d_out, int out_size, void* d_ws, size_t ws_size,
                              hipStream_t stream) {
    const float* X     = (const float*)d_in[0];
    const float* A     = (const float*)d_in[1];
    const float* W1    = (const float*)d_in[2];
    const float* W2    = (const float*)d_in[3];
    const float* alpha = (const float*)d_in[4];
    float* out = (float*)d_out;

    char* ws = (char*)d_ws;
    unsigned short* Gt = (unsigned short*)(ws);            // 2 MiB
    float* lvp   = (float*)(ws + 2097152);                 // 64 KiB
    float* rvp   = (float*)(ws + 2097152 + 65536);         // 64 KiB
    float* WcstG = (float*)(ws + 2097152 + 131072);        // 17408 B
    float* w1aG  = (float*)(ws + 2097152 + 131072 + 17408);// 512 B

    wc_kernel<<<1, 256, 0, stream>>>(W1, W2, alpha, WcstG, w1aG);
    prep_kernel<<<256, 256, 0, stream>>>(X, WcstG, w1aG, Gt, lvp, rvp);
    attn_kernel<<<256, 1024, 0, stream>>>(A, Gt, lvp, rvp, out);
}